// Round 1
// baseline (266.978 us; speedup 1.0000x reference)
//
#include <hip/hip_runtime.h>
#include <hip/hip_bf16.h>

typedef float f32x4 __attribute__((ext_vector_type(4)));
typedef short short8 __attribute__((ext_vector_type(8)));
typedef __bf16 bf16x8 __attribute__((ext_vector_type(8)));
typedef unsigned short u16;

#define LN2F 0.69314718055994531f

static __device__ __forceinline__ u16 f2bf(float f) {
    union { float f; unsigned u; } v; v.f = f;
    unsigned u = v.u;
    unsigned r = (u + 0x7fffu + ((u >> 16) & 1u)) >> 16;  // RNE
    return (u16)r;
}

static __device__ __forceinline__ float ssp(float x) {
    // softplus(x) - ln2, stable form: max(x,0) + log(1+exp(-|x|)) - ln2
    return fmaxf(x, 0.f) + __logf(1.f + __expf(-fabsf(x))) - LN2F;
}

static __device__ __forceinline__ f32x4 mfma16(short8 a, short8 b, f32x4 c) {
    return __builtin_amdgcn_mfma_f32_16x16x32_bf16(
        __builtin_bit_cast(bf16x8, a), __builtin_bit_cast(bf16x8, b), c, 0, 0, 0);
}

// Pack W1 (64x128) and W2 (128x128) into bf16 MFMA B-fragment order:
// frag element e of lane l for (ntile, kstep) holds W[k][g],
// k = kstep*32 + (l>>4)*8 + e, g = ntile*16 + (l&15).
__global__ void prep_kernel(const float* __restrict__ W1, const float* __restrict__ W2,
                            u16* __restrict__ w1f, u16* __restrict__ w2f) {
    int t = blockIdx.x * 256 + threadIdx.x;
    if (t < 8192) {  // 8 ntiles * 2 ksteps * 64 lanes * 8 elems
        int e = t & 7, l = (t >> 3) & 63, r = t >> 9;   // r = nt*2+ks
        int ks = r & 1, nt = r >> 1;
        int k = ks * 32 + (l >> 4) * 8 + e;
        int g = nt * 16 + (l & 15);
        w1f[t] = f2bf(W1[k * 128 + g]);
    }
    if (t < 16384) { // 8 ntiles * 4 ksteps * 64 lanes * 8 elems
        int e = t & 7, l = (t >> 3) & 63, r = t >> 9;   // r = nt*4+ks
        int ks = r & 3, nt = r >> 2;
        int k = ks * 32 + (l >> 4) * 8 + e;
        int g = nt * 16 + (l & 15);
        w2f[t] = f2bf(W2[k * 128 + g]);
    }
}

__global__ __launch_bounds__(256, 4)
void cfconv_kernel(const float* __restrict__ X, const float* __restrict__ R,
                   const float* __restrict__ Mask, const float* __restrict__ b1,
                   const float* __restrict__ b2, const u16* __restrict__ w1f,
                   const u16* __restrict__ w2f, float* __restrict__ out) {
    // XCD swizzle: blk%8 -> XCD, so each XCD handles exactly one batch b.
    int blk = blockIdx.x;
    int b = blk & 7;
    int i = blk >> 3;
    int tid = threadIdx.x;
    int w = tid >> 6, l = tid & 63;
    int row = l & 15, kq = l >> 4;

    __shared__ __align__(16) u16 rbfbuf[4][16 * 64];   // per-wave 16x64 bf16 A-tile
    __shared__ __align__(16) u16 h1buf[4][16 * 128];   // per-wave 16x128 bf16 H1 tile
    __shared__ float distbuf[4][48];
    __shared__ float outbuf[4][128];

    // --- distances for this wave's 48 j rows ---
    float rix = R[(b * 192 + i) * 3 + 0];
    float riy = R[(b * 192 + i) * 3 + 1];
    float riz = R[(b * 192 + i) * 3 + 2];
    if (l < 48) {
        int j = w * 48 + l;
        float dx = rix - R[(b * 192 + j) * 3 + 0];
        float dy = riy - R[(b * 192 + j) * 3 + 1];
        float dz = riz - R[(b * 192 + j) * 3 + 2];
        float d2 = dx * dx + dy * dy + dz * dz;
        distbuf[w][l] = (d2 > 0.f) ? sqrtf(d2) : 0.f;
    }

    float b1v[8], b2v[8];
#pragma unroll
    for (int nt = 0; nt < 8; ++nt) {
        b1v[nt] = b1[nt * 16 + row];
        b2v[nt] = b2[nt * 16 + row];
    }

    float racc[8] = {0.f, 0.f, 0.f, 0.f, 0.f, 0.f, 0.f, 0.f};

    const float MU_STEP = 30.0f / 63.0f;
    char* rb = (char*)&rbfbuf[w][0];
    char* hb = (char*)&h1buf[w][0];
    int sw = (row & 7) << 4;  // XOR swizzle for this lane's A-row

    for (int mt = 0; mt < 3; ++mt) {
        int jb = w * 48 + mt * 16;
        float d = distbuf[w][mt * 16 + row];

        // --- rbf tile: lane computes row=l&15, k in [kq*16, kq*16+16) ---
#pragma unroll
        for (int c = 0; c < 2; ++c) {
            short8 rv;
#pragma unroll
            for (int e = 0; e < 8; ++e) {
                float mu = (float)(kq * 16 + c * 8 + e) * MU_STEP;
                float t = mu - d;
                rv[e] = (short)f2bf(__expf(-10.f * t * t));
            }
            *(short8*)(rb + ((row * 128 + kq * 32 + c * 16) ^ sw)) = rv;
        }
        // A1 fragments (same for all ntiles): A[row][ks*32 + kq*8 + e]
        short8 a1_0 = *(short8*)(rb + ((row * 128 + 0 + kq * 16) ^ sw));
        short8 a1_1 = *(short8*)(rb + ((row * 128 + 64 + kq * 16) ^ sw));

        // --- GEMM1: H1 = ssp(rbf @ W1 + b1), stored bf16 to swizzled LDS ---
#pragma unroll
        for (int nt = 0; nt < 8; ++nt) {
            short8 bw0 = *(const short8*)(w1f + ((nt * 2 + 0) * 64 + l) * 8);
            short8 bw1 = *(const short8*)(w1f + ((nt * 2 + 1) * 64 + l) * 8);
            f32x4 c = {0.f, 0.f, 0.f, 0.f};
            c = mfma16(a1_0, bw0, c);
            c = mfma16(a1_1, bw1, c);
#pragma unroll
            for (int q = 0; q < 4; ++q) {
                int r2 = kq * 4 + q;  // C/D layout: row=(l>>4)*4+q, col=l&15
                float h = ssp(c[q] + b1v[nt]);
                *(u16*)(hb + ((r2 * 256 + (nt * 16 + row) * 2) ^ ((r2 & 7) << 4))) = f2bf(h);
            }
        }

        // A2 fragments: A[row][ks*32 + kq*8 + e] from h1buf
        short8 a2[4];
#pragma unroll
        for (int ks = 0; ks < 4; ++ks)
            a2[ks] = *(short8*)(hb + ((row * 256 + ks * 64 + kq * 16) ^ sw));

        // --- GEMM2 + ssp + X-weighted accumulate ---
#pragma unroll
        for (int nt = 0; nt < 8; ++nt) {
            f32x4 c = {0.f, 0.f, 0.f, 0.f};
#pragma unroll
            for (int ks = 0; ks < 4; ++ks) {
                short8 bw = *(const short8*)(w2f + ((nt * 4 + ks) * 64 + l) * 8);
                c = mfma16(a2[ks], bw, c);
            }
#pragma unroll
            for (int q = 0; q < 4; ++q) {
                float h = ssp(c[q] + b2v[nt]);
                float x = X[(b * 192 + jb + kq * 4 + q) * 128 + nt * 16 + row];
                racc[nt] = fmaf(h, x, racc[nt]);
            }
        }
    }

    // --- reduce over j: within wave (kq groups), then across waves ---
#pragma unroll
    for (int nt = 0; nt < 8; ++nt) {
        float v = racc[nt];
        v += __shfl_xor(v, 16, 64);
        v += __shfl_xor(v, 32, 64);
        if (l < 16) outbuf[w][nt * 16 + l] = v;
    }
    __syncthreads();
    if (tid < 128) {
        float o = outbuf[0][tid] + outbuf[1][tid] + outbuf[2][tid] + outbuf[3][tid];
        o *= Mask[b * 192 + i];
        out[(b * 192 + i) * 128 + tid] = o;
    }
}

extern "C" void kernel_launch(void* const* d_in, const int* in_sizes, int n_in,
                              void* d_out, int out_size, void* d_ws, size_t ws_size,
                              hipStream_t stream) {
    const float* X    = (const float*)d_in[0];
    const float* R    = (const float*)d_in[1];
    const float* Mask = (const float*)d_in[2];
    const float* W1   = (const float*)d_in[3];
    const float* b1   = (const float*)d_in[4];
    const float* W2   = (const float*)d_in[5];
    const float* b2   = (const float*)d_in[6];

    u16* w1f = (u16*)d_ws;          // 8192 bf16 = 16 KB
    u16* w2f = w1f + 8192;          // 16384 bf16 = 32 KB

    prep_kernel<<<64, 256, 0, stream>>>(W1, W2, w1f, w2f);
    cfconv_kernel<<<1536, 256, 0, stream>>>(X, R, Mask, b1, b2, w1f, w2f, (float*)d_out);
}

// Round 2
// 174.701 us; speedup vs baseline: 1.5282x; 1.5282x over previous
//
#include <hip/hip_runtime.h>
#include <hip/hip_bf16.h>

typedef float f32x4 __attribute__((ext_vector_type(4)));
typedef short short8 __attribute__((ext_vector_type(8)));
typedef __bf16 bf16x8 __attribute__((ext_vector_type(8)));
typedef unsigned short u16;

#define LN2F 0.69314718055994531f

static __device__ __forceinline__ u16 f2bf(float f) {
    union { float f; unsigned u; } v; v.f = f;
    unsigned u = v.u;
    unsigned r = (u + 0x7fffu + ((u >> 16) & 1u)) >> 16;  // RNE
    return (u16)r;
}

static __device__ __forceinline__ float ssp(float x) {
    // softplus(x) - ln2, stable: max(x,0) + log(1+exp(-|x|)) - ln2
    return fmaxf(x, 0.f) + __logf(1.f + __expf(-fabsf(x))) - LN2F;
}

static __device__ __forceinline__ f32x4 mfma16(short8 a, short8 b, f32x4 c) {
    return __builtin_amdgcn_mfma_f32_16x16x32_bf16(
        __builtin_bit_cast(bf16x8, a), __builtin_bit_cast(bf16x8, b), c, 0, 0, 0);
}

// Pack W1 (64x128) and W2 (128x128) into bf16 MFMA B-fragment order:
// frag element e of lane l for (ntile, kstep) holds W[k][g],
// k = kstep*32 + (l>>4)*8 + e, g = ntile*16 + (l&15).
__global__ void prep_kernel(const float* __restrict__ W1, const float* __restrict__ W2,
                            u16* __restrict__ w1f, u16* __restrict__ w2f) {
    int t = blockIdx.x * 256 + threadIdx.x;
    if (t < 8192) {  // 8 ntiles * 2 ksteps * 64 lanes * 8 elems
        int e = t & 7, l = (t >> 3) & 63, r = t >> 9;
        int ks = r & 1, nt = r >> 1;
        int k = ks * 32 + (l >> 4) * 8 + e;
        int g = nt * 16 + (l & 15);
        w1f[t] = f2bf(W1[k * 128 + g]);
    }
    if (t < 16384) { // 8 ntiles * 4 ksteps * 64 lanes * 8 elems
        int e = t & 7, l = (t >> 3) & 63, r = t >> 9;
        int ks = r & 3, nt = r >> 2;
        int k = ks * 32 + (l >> 4) * 8 + e;
        int g = nt * 16 + (l & 15);
        w2f[t] = f2bf(W2[k * 128 + g]);
    }
}

__global__ __launch_bounds__(256, 2)
void cfconv_kernel(const float* __restrict__ X, const float* __restrict__ R,
                   const float* __restrict__ Mask, const float* __restrict__ b1,
                   const float* __restrict__ b2, const u16* __restrict__ wsrc,
                   float* __restrict__ out) {
    // XCD swizzle: blk%8 -> XCD heuristic; one batch b per XCD.
    int blk = blockIdx.x;
    int b = blk & 7;
    int i = blk >> 3;
    int tid = threadIdx.x;
    int w = tid >> 6, l = tid & 63;
    int row = l & 15, kq = l >> 4;

    __shared__ __align__(16) u16 wlds[24576];      // 48KB: w1f [0,8192), w2f [8192,24576)
    __shared__ __align__(16) u16 h1buf[4][2048];   // per-wave 16x128 bf16 H1 tile
    __shared__ float outbuf[4][128];

    // --- stage weight fragments (48KB, linear) into LDS: 48 chunks of 1KB ---
#pragma unroll
    for (int c = 0; c < 12; ++c) {
        int chunk = c * 4 + w;
        __builtin_amdgcn_global_load_lds(
            (const __attribute__((address_space(1))) void*)((const char*)wsrc + chunk * 1024 + l * 16),
            (__attribute__((address_space(3))) void*)((char*)wlds + chunk * 1024),
            16, 0, 0);
    }

    // --- distances: lane l (<48) computes dist for j = w*48+l ---
    float rix = R[(b * 192 + i) * 3 + 0];
    float riy = R[(b * 192 + i) * 3 + 1];
    float riz = R[(b * 192 + i) * 3 + 2];
    float dval;
    {
        int j = w * 48 + (l < 48 ? l : 47);
        float dx = rix - R[(b * 192 + j) * 3 + 0];
        float dy = riy - R[(b * 192 + j) * 3 + 1];
        float dz = riz - R[(b * 192 + j) * 3 + 2];
        float d2 = dx * dx + dy * dy + dz * dz;
        dval = (d2 > 0.f) ? sqrtf(d2) : 0.f;
    }

    float b1v[8], b2v[8];
#pragma unroll
    for (int nt = 0; nt < 8; ++nt) {
        b1v[nt] = b1[nt * 16 + row];
        b2v[nt] = b2[nt * 16 + row];
    }

    float racc[8] = {0.f, 0.f, 0.f, 0.f, 0.f, 0.f, 0.f, 0.f};

    asm volatile("s_waitcnt vmcnt(0)" ::: "memory");
    __syncthreads();

    const float MU_STEP = 30.0f / 63.0f;
    char* hb = (char*)&h1buf[w][0];
    int sw = (row & 7) << 4;

    for (int mt = 0; mt < 3; ++mt) {
        int jb = w * 48 + mt * 16;
        float d = __shfl(dval, mt * 16 + row, 64);

        // --- rbf A-fragments computed directly in-register ---
        short8 a1[2];
#pragma unroll
        for (int ks = 0; ks < 2; ++ks)
#pragma unroll
            for (int e = 0; e < 8; ++e) {
                float t = (float)(ks * 32 + kq * 8 + e) * MU_STEP - d;
                a1[ks][e] = (short)f2bf(__expf(-10.f * t * t));
            }

        // --- GEMM1: H1 = ssp(rbf @ W1 + b1) -> swizzled LDS (bf16) ---
#pragma unroll
        for (int nt = 0; nt < 8; ++nt) {
            short8 bw0 = *(const short8*)(wlds + ((nt * 2 + 0) * 64 + l) * 8);
            short8 bw1 = *(const short8*)(wlds + ((nt * 2 + 1) * 64 + l) * 8);
            f32x4 c = {0.f, 0.f, 0.f, 0.f};
            c = mfma16(a1[0], bw0, c);
            c = mfma16(a1[1], bw1, c);
#pragma unroll
            for (int q = 0; q < 4; ++q) {
                int r2 = kq * 4 + q;  // C/D: row=(l>>4)*4+q, col=l&15
                float h = ssp(c[q] + b1v[nt]);
                *(u16*)(hb + ((r2 * 256 + (nt * 16 + row) * 2) ^ ((r2 & 7) << 4))) = f2bf(h);
            }
        }

        // --- A2 fragments from h1buf ---
        short8 a2[4];
#pragma unroll
        for (int ks = 0; ks < 4; ++ks)
            a2[ks] = *(short8*)(hb + ((row * 256 + ks * 64 + kq * 16) ^ sw));

        // --- preload X values for this mt ---
        float xv[8][4];
#pragma unroll
        for (int nt = 0; nt < 8; ++nt)
#pragma unroll
            for (int q = 0; q < 4; ++q)
                xv[nt][q] = X[(b * 192 + jb + kq * 4 + q) * 128 + nt * 16 + row];

        // --- GEMM2 + ssp + X-weighted accumulate ---
#pragma unroll
        for (int nt = 0; nt < 8; ++nt) {
            f32x4 c = {0.f, 0.f, 0.f, 0.f};
#pragma unroll
            for (int ks = 0; ks < 4; ++ks) {
                short8 bw = *(const short8*)(wlds + 8192 + ((nt * 4 + ks) * 64 + l) * 8);
                c = mfma16(a2[ks], bw, c);
            }
#pragma unroll
            for (int q = 0; q < 4; ++q) {
                float h = ssp(c[q] + b2v[nt]);
                racc[nt] = fmaf(h, xv[nt][q], racc[nt]);
            }
        }
    }

    // --- reduce over j: within wave (kq groups), then across waves ---
#pragma unroll
    for (int nt = 0; nt < 8; ++nt) {
        float v = racc[nt];
        v += __shfl_xor(v, 16, 64);
        v += __shfl_xor(v, 32, 64);
        if (l < 16) outbuf[w][nt * 16 + l] = v;
    }
    __syncthreads();
    if (tid < 128) {
        float o = outbuf[0][tid] + outbuf[1][tid] + outbuf[2][tid] + outbuf[3][tid];
        o *= Mask[b * 192 + i];
        out[(b * 192 + i) * 128 + tid] = o;
    }
}

extern "C" void kernel_launch(void* const* d_in, const int* in_sizes, int n_in,
                              void* d_out, int out_size, void* d_ws, size_t ws_size,
                              hipStream_t stream) {
    const float* X    = (const float*)d_in[0];
    const float* R    = (const float*)d_in[1];
    const float* Mask = (const float*)d_in[2];
    const float* W1   = (const float*)d_in[3];
    const float* b1   = (const float*)d_in[4];
    const float* W2   = (const float*)d_in[5];
    const float* b2   = (const float*)d_in[6];

    u16* w1f = (u16*)d_ws;          // 8192 bf16 = 16 KB
    u16* w2f = w1f + 8192;          // 16384 bf16 = 32 KB (contiguous with w1f)

    prep_kernel<<<64, 256, 0, stream>>>(W1, W2, w1f, w2f);
    cfconv_kernel<<<1536, 256, 0, stream>>>(X, R, Mask, b1, b2, w1f, (float*)d_out);
}

// Round 3
// 114.461 us; speedup vs baseline: 2.3325x; 1.5263x over previous
//
#include <hip/hip_runtime.h>
#include <hip/hip_bf16.h>

typedef float f32x4 __attribute__((ext_vector_type(4)));
typedef short short8 __attribute__((ext_vector_type(8)));
typedef __bf16 bf16x8 __attribute__((ext_vector_type(8)));
typedef unsigned u32;
typedef unsigned short u16;

#define LN2F 0.69314718055994531f
#define MU_STEP (30.0f / 63.0f)

union S8 { u32 w[4]; short8 s; };

static __device__ __forceinline__ float ssp(float x) {
    // softplus(x) - ln2, stable: max(x,0) + log(1+exp(-|x|)) - ln2
    return fmaxf(x, 0.f) + __logf(1.f + __expf(-fabsf(x))) - LN2F;
}
static __device__ __forceinline__ u32 pkbf(float a, float b) {
    union { __bf16 h[2]; u32 u; } z;
    z.h[0] = (__bf16)a; z.h[1] = (__bf16)b;
    return z.u;
}
static __device__ __forceinline__ u16 f2bf(float f) {
    union { float f; unsigned u; } v; v.f = f;
    unsigned u = v.u;
    unsigned r = (u + 0x7fffu + ((u >> 16) & 1u)) >> 16;  // RNE
    return (u16)r;
}
static __device__ __forceinline__ f32x4 mfma16(short8 a, short8 b, f32x4 c) {
    return __builtin_amdgcn_mfma_f32_16x16x32_bf16(
        __builtin_bit_cast(bf16x8, a), __builtin_bit_cast(bf16x8, b), c, 0, 0, 0);
}

// Pack W1 (64x128) and W2 (128x128) into bf16 MFMA fragment order:
// element e of lane l for (tile, kstep) holds W[k][g],
// k = kstep*32 + (l>>4)*8 + e, g = tile*16 + (l&15).
// (Serves as B-frag for normal GEMM and as A-frag for the transposed GEMM.)
__global__ void prep_kernel(const float* __restrict__ W1, const float* __restrict__ W2,
                            u16* __restrict__ w1f, u16* __restrict__ w2f) {
    int t = blockIdx.x * 256 + threadIdx.x;
    if (t < 8192) {  // 8 tiles * 2 ksteps * 64 lanes * 8 elems
        int e = t & 7, l = (t >> 3) & 63, r = t >> 9;
        int ks = r & 1, nt = r >> 1;
        int k = ks * 32 + (l >> 4) * 8 + e;
        int g = nt * 16 + (l & 15);
        w1f[t] = f2bf(W1[k * 128 + g]);
    }
    if (t < 16384) { // 8 tiles * 4 ksteps * 64 lanes * 8 elems
        int e = t & 7, l = (t >> 3) & 63, r = t >> 9;
        int ks = r & 3, nt = r >> 2;
        int k = ks * 32 + (l >> 4) * 8 + e;
        int g = nt * 16 + (l & 15);
        w2f[t] = f2bf(W2[k * 128 + g]);
    }
}

__global__ __launch_bounds__(256, 3)
void cfconv_kernel(const float* __restrict__ X, const float* __restrict__ R,
                   const float* __restrict__ Mask, const float* __restrict__ b1,
                   const float* __restrict__ b2, const u16* __restrict__ wsrc,
                   float* __restrict__ out) {
    int blk = blockIdx.x;
    int b = blk & 7;           // XCD round-robin: one batch per XCD
    int ip = blk >> 3;         // 0..95 -> i pair
    int i0 = ip * 2;
    int tid = threadIdx.x;
    int w = tid >> 6, l = tid & 63;
    int r15 = l & 15, kq = l >> 4;

    __shared__ __align__(16) char smem[50176];
    u16* wlds = (u16*)smem;                 // 48KB: w1f [0,8192), w2f [8192,24576)
    float* bias = (float*)(smem + 49152);   // 1KB: b1 [0,128), b2 [128,256)
    float* outbuf = (float*)smem;           // aliased after barrier: [w][i][g]=[4][2][128]

    // --- stage weight fragments (48KB linear) ---
#pragma unroll
    for (int c = 0; c < 12; ++c) {
        int chunk = c * 4 + w;
        __builtin_amdgcn_global_load_lds(
            (const __attribute__((address_space(1))) void*)((const char*)wsrc + chunk * 1024 + l * 16),
            (__attribute__((address_space(3))) void*)(smem + chunk * 1024),
            16, 0, 0);
    }
    if (tid < 128) { bias[tid] = b1[tid]; bias[128 + tid] = b2[tid]; }

    // --- distances for both i's; lane l (<48) owns j = w*48+l ---
    float dv0, dv1;
    {
        int j = w * 48 + (l < 48 ? l : 0);
        const float* Rb = R + (size_t)b * 576;
        float jx = Rb[j * 3], jy = Rb[j * 3 + 1], jz = Rb[j * 3 + 2];
        float ax = Rb[i0 * 3], ay = Rb[i0 * 3 + 1], az = Rb[i0 * 3 + 2];
        float cx = Rb[i0 * 3 + 3], cy = Rb[i0 * 3 + 4], cz = Rb[i0 * 3 + 5];
        float d2 = (ax - jx) * (ax - jx) + (ay - jy) * (ay - jy) + (az - jz) * (az - jz);
        dv0 = d2 > 0.f ? sqrtf(d2) : 0.f;
        d2 = (cx - jx) * (cx - jx) + (cy - jy) * (cy - jy) + (cz - jz) * (cz - jz);
        dv1 = d2 > 0.f ? sqrtf(d2) : 0.f;
    }

    float b2v[8];
#pragma unroll
    for (int nt = 0; nt < 8; ++nt) b2v[nt] = b2[nt * 16 + r15];

    float racc0[8] = {0, 0, 0, 0, 0, 0, 0, 0};
    float racc1[8] = {0, 0, 0, 0, 0, 0, 0, 0};

    asm volatile("s_waitcnt vmcnt(0)" ::: "memory");
    __syncthreads();

    const float* Xb = X + (size_t)b * 192 * 128;
    int srcA = ((kq & 1) * 2) * 16 + r15;   // shfl src for words 0,1
    int srcB = srcA + 16;                   // shfl src for words 2,3
    bool hi = (kq >> 1) != 0;

    for (int mt = 0; mt < 3; ++mt) {
        int jb = w * 48 + mt * 16;
        float d0 = __shfl(dv0, mt * 16 + r15, 64);
        float d1 = __shfl(dv1, mt * 16 + r15, 64);

        // --- rbf^T B-frags in-register: lane holds rbf[j=r15][k=ks*32+kq*8+e] ---
        S8 rb0[2], rb1[2];
#pragma unroll
        for (int ks = 0; ks < 2; ++ks)
#pragma unroll
            for (int wd = 0; wd < 4; ++wd) {
                float mu0 = (float)(ks * 32 + kq * 8 + wd * 2) * MU_STEP;
                float mu1 = mu0 + MU_STEP;
                float tA = mu0 - d0, tB = mu1 - d0, tC = mu0 - d1, tD = mu1 - d1;
                rb0[ks].w[wd] = pkbf(__expf(-10.f * tA * tA), __expf(-10.f * tB * tB));
                rb1[ks].w[wd] = pkbf(__expf(-10.f * tC * tC), __expf(-10.f * tD * tD));
            }

        // --- GEMM1 (transposed): C1[ft] = W1^T tile @ rbf^T; ssp; pack; shfl-transpose ---
        S8 A20[4], A21[4];   // A-frags for GEMM2, per kstep
#pragma unroll
        for (int h = 0; h < 2; ++h) {
            u32 pk0[4][2], pk1[4][2];
#pragma unroll
            for (int f4 = 0; f4 < 4; ++f4) {
                int ft = h * 4 + f4;
                short8 A0 = *(const short8*)(wlds + ((ft * 2 + 0) * 64 + l) * 8);
                short8 A1 = *(const short8*)(wlds + ((ft * 2 + 1) * 64 + l) * 8);
                f32x4 c0 = {0, 0, 0, 0}, c1 = {0, 0, 0, 0};
                c0 = mfma16(A0, rb0[0].s, c0);
                c0 = mfma16(A1, rb0[1].s, c0);
                c1 = mfma16(A0, rb1[0].s, c1);
                c1 = mfma16(A1, rb1[1].s, c1);
                f32x4 bb = *(const f32x4*)(bias + ft * 16 + kq * 4);
                float h00 = ssp(c0[0] + bb[0]), h01 = ssp(c0[1] + bb[1]);
                float h02 = ssp(c0[2] + bb[2]), h03 = ssp(c0[3] + bb[3]);
                float h10 = ssp(c1[0] + bb[0]), h11 = ssp(c1[1] + bb[1]);
                float h12 = ssp(c1[2] + bb[2]), h13 = ssp(c1[3] + bb[3]);
                pk0[f4][0] = pkbf(h00, h01); pk0[f4][1] = pkbf(h02, h03);
                pk1[f4][0] = pkbf(h10, h11); pk1[f4][1] = pkbf(h12, h13);
            }
            // transpose: A2[ks].w[wd] = H1[j=r15][f=ks*32+kq*8+{2wd,2wd+1}]
#pragma unroll
            for (int kh = 0; kh < 2; ++kh) {
                int ks = h * 2 + kh;
#pragma unroll
                for (int wd = 0; wd < 4; ++wd) {
                    int src = (wd >> 1) ? srcB : srcA;
                    int ws = wd & 1;
                    u32 vE0 = (u32)__shfl((int)pk0[2 * kh][ws], src, 64);
                    u32 vO0 = (u32)__shfl((int)pk0[2 * kh + 1][ws], src, 64);
                    A20[ks].w[wd] = hi ? vO0 : vE0;
                    u32 vE1 = (u32)__shfl((int)pk1[2 * kh][ws], src, 64);
                    u32 vO1 = (u32)__shfl((int)pk1[2 * kh + 1][ws], src, 64);
                    A21[ks].w[wd] = hi ? vO1 : vE1;
                }
            }
        }

        // --- GEMM2 (normal) + ssp + X-weighted accumulate ---
        const float* Xrow = Xb + (size_t)(jb + kq * 4) * 128;
#pragma unroll
        for (int nt = 0; nt < 8; ++nt) {
            float xv0 = Xrow[0 * 128 + nt * 16 + r15];
            float xv1 = Xrow[1 * 128 + nt * 16 + r15];
            float xv2 = Xrow[2 * 128 + nt * 16 + r15];
            float xv3 = Xrow[3 * 128 + nt * 16 + r15];
            f32x4 e0 = {0, 0, 0, 0}, e1 = {0, 0, 0, 0};
#pragma unroll
            for (int ks = 0; ks < 4; ++ks) {
                short8 bw = *(const short8*)(wlds + 8192 + ((nt * 4 + ks) * 64 + l) * 8);
                e0 = mfma16(A20[ks].s, bw, e0);
                e1 = mfma16(A21[ks].s, bw, e1);
            }
            float bb = b2v[nt];
            racc0[nt] += ssp(e0[0] + bb) * xv0 + ssp(e0[1] + bb) * xv1
                       + ssp(e0[2] + bb) * xv2 + ssp(e0[3] + bb) * xv3;
            racc1[nt] += ssp(e1[0] + bb) * xv0 + ssp(e1[1] + bb) * xv1
                       + ssp(e1[2] + bb) * xv2 + ssp(e1[3] + bb) * xv3;
        }
    }

    __syncthreads();   // all wlds reads done before aliasing smem as outbuf
#pragma unroll
    for (int nt = 0; nt < 8; ++nt) {
        float v0 = racc0[nt], v1 = racc1[nt];
        v0 += __shfl_xor(v0, 16, 64); v0 += __shfl_xor(v0, 32, 64);
        v1 += __shfl_xor(v1, 16, 64); v1 += __shfl_xor(v1, 32, 64);
        if (l < 16) {
            outbuf[(w * 2 + 0) * 128 + nt * 16 + l] = v0;
            outbuf[(w * 2 + 1) * 128 + nt * 16 + l] = v1;
        }
    }
    __syncthreads();
    {
        int ii = tid >> 7, g = tid & 127;
        float o = outbuf[(0 * 2 + ii) * 128 + g] + outbuf[(1 * 2 + ii) * 128 + g]
                + outbuf[(2 * 2 + ii) * 128 + g] + outbuf[(3 * 2 + ii) * 128 + g];
        o *= Mask[b * 192 + i0 + ii];
        out[((size_t)b * 192 + i0 + ii) * 128 + g] = o;
    }
}

extern "C" void kernel_launch(void* const* d_in, const int* in_sizes, int n_in,
                              void* d_out, int out_size, void* d_ws, size_t ws_size,
                              hipStream_t stream) {
    const float* X    = (const float*)d_in[0];
    const float* R    = (const float*)d_in[1];
    const float* Mask = (const float*)d_in[2];
    const float* W1   = (const float*)d_in[3];
    const float* b1   = (const float*)d_in[4];
    const float* W2   = (const float*)d_in[5];
    const float* b2   = (const float*)d_in[6];

    u16* w1f = (u16*)d_ws;          // 8192 bf16 = 16 KB
    u16* w2f = w1f + 8192;          // 16384 bf16 = 32 KB (contiguous)

    prep_kernel<<<64, 256, 0, stream>>>(W1, W2, w1f, w2f);
    cfconv_kernel<<<768, 256, 0, stream>>>(X, R, Mask, b1, b2, w1f, (float*)d_out);
}

// Round 4
// 35.661 us; speedup vs baseline: 7.4866x; 3.2097x over previous
//
#include <hip/hip_runtime.h>

#define MU_STEP (30.0f / 63.0f)
#define LN2F 0.69314718055994531f

static __device__ __forceinline__ float ssp(float x) {
    // softplus(x) - ln2, stable: max(x,0) + log(1+exp(-|x|)) - ln2
    return fmaxf(x, 0.f) + __logf(1.f + __expf(-fabsf(x))) - LN2F;
}

// Build T[k][g] = ssp(ssp(rbf(d_k)@W1 + b1)@W2 + b2), d_k = k*hstep, 4 k's/block.
__global__ __launch_bounds__(256, 4)
void build_table(const float* __restrict__ W1, const float* __restrict__ b1,
                 const float* __restrict__ W2, const float* __restrict__ b2,
                 float* __restrict__ T, int nk, float hstep) {
    __shared__ float rbf[4][64];
    __shared__ float h1[4][128];
    int t = threadIdx.x;
    int k0 = blockIdx.x * 4;

    for (int it = t; it < 4 * 64; it += 256) {
        int kk = it >> 6, m = it & 63;
        float d = (float)(k0 + kk) * hstep;
        float tt = (float)m * MU_STEP - d;
        rbf[kk][m] = __expf(-10.f * tt * tt);
    }
    __syncthreads();
    for (int it = t; it < 4 * 128; it += 256) {
        int kk = it >> 7, f = it & 127;
        float a = b1[f];
#pragma unroll 8
        for (int m = 0; m < 64; ++m)
            a = fmaf(rbf[kk][m], W1[m * 128 + f], a);
        h1[kk][f] = ssp(a);
    }
    __syncthreads();
    for (int it = t; it < 4 * 128; it += 256) {
        int kk = it >> 7, g = it & 127;
        float a = b2[g];
#pragma unroll 8
        for (int f = 0; f < 128; ++f)
            a = fmaf(h1[kk][f], W2[f * 128 + g], a);
        T[(size_t)(k0 + kk) * 128 + g] = ssp(a);
    }
}

// One block per (b,i). 256 threads: g = tid&127, half = tid>>7 owns 96 j's.
__global__ __launch_bounds__(256, 6)
void cfconv_main(const float* __restrict__ X, const float* __restrict__ R,
                 const float* __restrict__ Mask, const float* __restrict__ T,
                 float* __restrict__ out, int nk, float scale) {
    int blk = blockIdx.x;
    int b = blk & 7;          // XCD round-robin heuristic: one batch per XCD
    int i = blk >> 3;
    int tid = threadIdx.x;
    int g = tid & 127, half = tid >> 7;

    __shared__ int2 kfl[192];    // {row byte offset k*512, bits of frac f}
    __shared__ float part[128];

    if (tid < 192) {
        const float* Rb = R + b * 576;
        float ix = Rb[i * 3 + 0], iy = Rb[i * 3 + 1], iz = Rb[i * 3 + 2];
        float dx = ix - Rb[tid * 3 + 0];
        float dy = iy - Rb[tid * 3 + 1];
        float dz = iz - Rb[tid * 3 + 2];
        float d2 = dx * dx + dy * dy + dz * dz;
        float d = d2 > 0.f ? sqrtf(d2) : 0.f;
        float u = d * scale;
        int k = (int)u;
        if (k > nk - 2) k = nk - 2;
        float f = u - (float)k;
        kfl[tid] = make_int2(k * 512, __float_as_int(f));
    }
    __syncthreads();

    int j0 = half * 96;
    unsigned g4 = (unsigned)g * 4u;
    const char* Tb = (const char*)T;
    const float* Xp = X + (size_t)b * 24576 + (size_t)j0 * 128 + g;
    float acc = 0.f;

    for (int jj = 0; jj < 96; jj += 8) {
        const float* Xg = Xp + jj * 128;
#pragma unroll
        for (int e = 0; e < 8; ++e) {
            int2 kf2 = kfl[j0 + jj + e];           // same addr across lanes: broadcast
            float f = __int_as_float(kf2.y);
            unsigned off = (unsigned)kf2.x + g4;   // uniform base + 32-bit voffset
            float t0 = *(const float*)(Tb + off);
            float t1 = *(const float*)(Tb + off + 512u);
            float x = Xg[e * 128];
            acc = fmaf(t0 + f * (t1 - t0), x, acc);
        }
    }

    if (half == 1) part[g] = acc;
    __syncthreads();
    if (half == 0) {
        float o = (acc + part[g]) * Mask[b * 192 + i];
        out[((size_t)b * 192 + i) * 128 + g] = o;
    }
}

extern "C" void kernel_launch(void* const* d_in, const int* in_sizes, int n_in,
                              void* d_out, int out_size, void* d_ws, size_t ws_size,
                              hipStream_t stream) {
    const float* X    = (const float*)d_in[0];
    const float* R    = (const float*)d_in[1];
    const float* Mask = (const float*)d_in[2];
    const float* W1   = (const float*)d_in[3];
    const float* b1   = (const float*)d_in[4];
    const float* W2   = (const float*)d_in[5];
    const float* b2   = (const float*)d_in[6];

    // Table lives in d_ws: nk rows x 128 f32 (512 B/row). Target nk=4096 (2 MB);
    // shrink to fit ws_size if needed (accuracy degrades ~quadratically in 1/nk).
    int nk = 4096;
    size_t maxrows = ws_size / 512;
    if ((size_t)nk > maxrows) nk = (int)(maxrows & ~(size_t)3);
    if (nk < 8) nk = 8;
    float hstep = 30.0f / (float)(nk - 1);
    float scale = (float)(nk - 1) / 30.0f;
    float* T = (float*)d_ws;

    build_table<<<nk / 4, 256, 0, stream>>>(W1, b1, W2, b2, T, nk, hstep);
    cfconv_main<<<1536, 256, 0, stream>>>(X, R, Mask, T, (float*)d_out, nk, scale);
}